// Round 10
// baseline (763.536 us; speedup 1.0000x reference)
//
#include <hip/hip_runtime.h>
#include <hip/hip_bf16.h>

typedef __hip_bfloat16 bf16;

#define NN 100000
#define NE 1600000
#define DD 64
#define NL 3
#define NG 128
#define BN_EPS 1e-5f
#define NBLK_GATHER 2048
#define SCAN_BLK 98  // ceil(NN / 1024)
#define TILE_ROWS 64
#define NT ((NN + TILE_ROWS - 1) / TILE_ROWS)  // 1563

// ---------------- dtype detect (int64 vs int32) + identity BN slot init ----------------
__global__ __launch_bounds__(256) void detect_kernel(const int* __restrict__ ei,
                                                     const int* __restrict__ batch,
                                                     int* __restrict__ flags,
                                                     float* __restrict__ stats0) {
    if (threadIdx.x < 64) stats0[threadIdx.x] = 1.0f;
    else if (threadIdx.x < 128) stats0[threadIdx.x] = 0.0f;

    __shared__ int s_e, s_b;
    if (threadIdx.x == 0) { s_e = 0; s_b = 0; }
    __syncthreads();
    for (int i = threadIdx.x; i < 512; i += 256) {
        if (ei[2 * i + 1] != 0) atomicOr(&s_e, 1);
        if (batch[NN - 1024 + 2 * i + 1] != 0) atomicOr(&s_b, 1);
    }
    __syncthreads();
    if (threadIdx.x == 0) { flags[0] = s_e; flags[1] = s_b; }  // 1 = int32, 0 = int64
}

__device__ __forceinline__ int ld_src(const int* ei, int e, int is32) {
    return is32 ? ei[e] : ei[2 * e];
}
__device__ __forceinline__ int ld_dst(const int* ei, int e, int is32) {
    return is32 ? ei[NE + e] : ei[2 * NE + 2 * e];
}
__device__ __forceinline__ int ld_batch(const int* b, int n, int is32) {
    return is32 ? b[n] : b[2 * n];
}

// ---------------- degree (int) ----------------
__global__ __launch_bounds__(256) void deg_kernel(const int* __restrict__ ei,
                                                  const int* __restrict__ flags,
                                                  int* __restrict__ deg_cnt) {
    int is32 = flags[0];
    int e = blockIdx.x * 256 + threadIdx.x;
    if (e < NE) atomicAdd(&deg_cnt[ld_dst(ei, e, is32)], 1);
}

// ---------------- parallel exclusive scan of degrees -> rowptr (+ fused dinv) ----------------
__global__ __launch_bounds__(256) void scan_part_kernel(const int* __restrict__ deg_cnt,
                                                        int* __restrict__ blocksum,
                                                        float* __restrict__ dinv) {
    __shared__ int s[256];
    int base = blockIdx.x * 1024 + threadIdx.x * 4;
    int t = 0;
    if (base < NN) {  // NN % 4 == 0 -> whole int4 in-bounds
        int4 v = *(const int4*)(deg_cnt + base);
        t = v.x + v.y + v.z + v.w;
        float4 dv = make_float4(rsqrtf((float)v.x + 1.f), rsqrtf((float)v.y + 1.f),
                                rsqrtf((float)v.z + 1.f), rsqrtf((float)v.w + 1.f));
        *(float4*)(dinv + base) = dv;  // +1 self-loop
    }
    s[threadIdx.x] = t;
    __syncthreads();
    for (int off = 128; off > 0; off >>= 1) {
        if (threadIdx.x < off) s[threadIdx.x] += s[threadIdx.x + off];
        __syncthreads();
    }
    if (threadIdx.x == 0) blocksum[blockIdx.x] = s[0];
}

__global__ __launch_bounds__(128) void scan_mid_kernel(int* __restrict__ blocksum,
                                                       int* __restrict__ rowptr) {
    __shared__ int s[128];
    int tid = threadIdx.x;
    int v = (tid < SCAN_BLK) ? blocksum[tid] : 0;
    s[tid] = v;
    for (int off = 1; off < 128; off <<= 1) {
        __syncthreads();
        int a = (tid >= off) ? s[tid - off] : 0;
        __syncthreads();
        s[tid] += a;
    }
    __syncthreads();
    if (tid < SCAN_BLK) blocksum[tid] = s[tid] - v;  // exclusive
    if (tid == 127) rowptr[NN] = s[127];             // total == NE
}

__global__ __launch_bounds__(256) void scan_write_kernel(int* __restrict__ deg_cnt,
                                                         const int* __restrict__ blocksum,
                                                         int* __restrict__ rowptr) {
    __shared__ int s[256];
    int base = blockIdx.x * 1024 + threadIdx.x * 4;
    int4 v = make_int4(0, 0, 0, 0);
    if (base < NN) v = *(const int4*)(deg_cnt + base);
    int t = v.x + v.y + v.z + v.w;
    s[threadIdx.x] = t;
    for (int off = 1; off < 256; off <<= 1) {
        __syncthreads();
        int a = (threadIdx.x >= off) ? s[threadIdx.x - off] : 0;
        __syncthreads();
        s[threadIdx.x] += a;
    }
    __syncthreads();
    int pre = blocksum[blockIdx.x] + s[threadIdx.x] - t;  // exclusive prefix
    if (base < NN) {
        rowptr[base] = pre;
        rowptr[base + 1] = pre + v.x;
        rowptr[base + 2] = pre + v.x + v.y;
        rowptr[base + 3] = pre + v.x + v.y + v.z;
        *(int4*)(deg_cnt + base) = make_int4(0, 0, 0, 0);
    }
}

// ---------------- CSR fill: interleaved (src, weight) ----------------
__global__ __launch_bounds__(256) void fill_kernel(const int* __restrict__ ei,
                                                   const int* __restrict__ flags,
                                                   const float* __restrict__ dinv,
                                                   const int* __restrict__ rowptr,
                                                   int* __restrict__ cursor,
                                                   int2* __restrict__ csw) {
    int is32 = flags[0];
    int e = blockIdx.x * 256 + threadIdx.x;
    if (e >= NE) return;
    int s = ld_src(ei, e, is32), d = ld_dst(ei, e, is32);
    int pos = rowptr[d] + atomicAdd(&cursor[d], 1);
    float w = dinv[s] * dinv[d];
    csw[pos] = make_int2(s, __float_as_int(w));
}

// ---------------- LDS-tiled gemm: t_bf16 = act(BN(h)) @ W ----------------
__global__ __launch_bounds__(256) void gemm_kernel(const float* __restrict__ h,
                                                   const float* __restrict__ W,
                                                   const float* __restrict__ stats_l,
                                                   float alpha,
                                                   bf16* __restrict__ t,
                                                   float* __restrict__ accum_l) {
    if (blockIdx.x == 0 && threadIdx.x < 128) accum_l[threadIdx.x] = 0.f;

    __shared__ float ls[TILE_ROWS * DD];  // 16 KB staged tile (post-activation)
    __shared__ float ssc[DD], ssh[DD];
    if (threadIdx.x < 64) ssc[threadIdx.x] = stats_l[threadIdx.x];
    else if (threadIdx.x < 128) ssh[threadIdx.x - 64] = stats_l[threadIdx.x];

    int c = threadIdx.x & 63;
    int wv = threadIdx.x >> 6;  // wave id 0..3
    float w[DD];
#pragma unroll
    for (int k = 0; k < DD; ++k) w[k] = W[k * DD + c];
    __syncthreads();  // ssc/ssh ready

    for (int tile = blockIdx.x; tile < NT; tile += gridDim.x) {
        int row0 = tile * TILE_ROWS;
#pragma unroll
        for (int it = 0; it < 4; ++it) {
            int flat = (threadIdx.x + it * 256) * 4;  // 0..16380
            int gflat = row0 * DD + flat;
            if (gflat < NN * DD) {
                float4 hv = *(const float4*)(h + gflat);
                int c0 = flat & 63;
                float4 s4 = *(const float4*)(ssc + c0);
                float4 b4 = *(const float4*)(ssh + c0);
                float x0 = hv.x * s4.x + b4.x;
                float x1 = hv.y * s4.y + b4.y;
                float x2 = hv.z * s4.z + b4.z;
                float x3 = hv.w * s4.w + b4.w;
                x0 = fmaxf(x0, x0 * alpha);
                x1 = fmaxf(x1, x1 * alpha);
                x2 = fmaxf(x2, x2 * alpha);
                x3 = fmaxf(x3, x3 * alpha);
                *(float4*)(ls + flat) = make_float4(x0, x1, x2, x3);
            }
        }
        __syncthreads();
        int nrows = min(TILE_ROWS, NN - row0);
        int rend = min(wv * 16 + 16, nrows);
        for (int rl = wv * 16; rl < rend; ++rl) {
            const float4* hrow = (const float4*)(ls + rl * DD);
            float acc = 0.f;
#pragma unroll
            for (int kk = 0; kk < DD / 4; ++kk) {
                float4 hv = hrow[kk];  // wave-uniform LDS read -> broadcast
                acc += hv.x * w[4 * kk] + hv.y * w[4 * kk + 1] +
                       hv.z * w[4 * kk + 2] + hv.w * w[4 * kk + 3];
            }
            t[(size_t)(row0 + rl) * DD + c] = __float2bfloat16(acc);
        }
        __syncthreads();
    }
}

// ---------------- gather: 2 features/lane, half-waves process disjoint edges ----------------
// Lane layout: half = lane>>5, sl = lane&31; lane covers features (2sl, 2sl+1).
// One 64-lane uint load fetches TWO neighbor rows (256 B) -> half the vmem
// instructions, 16 edges in flight per unrolled batch.
__global__ __launch_bounds__(256) void gather_kernel(const bf16* __restrict__ t,
                                                     const float* __restrict__ dinv,
                                                     const float* __restrict__ bias,
                                                     const int* __restrict__ rowptr,
                                                     const int2* __restrict__ csw,
                                                     float* __restrict__ h,
                                                     float* __restrict__ accum_l) {
    const unsigned int* t2 = (const unsigned int*)t;  // 1 uint = 2 bf16 features
    int lane = threadIdx.x & 63;
    int wv = threadIdx.x >> 6;
    int half = lane >> 5;
    int sl = lane & 31;
    float2 bb = ((const float2*)bias)[sl];
    int wave = blockIdx.x * 4 + wv;
    float sumA = 0.f, sqA = 0.f, sumB = 0.f, sqB = 0.f;
    for (int d = wave; d < NN; d += NBLK_GATHER * 4) {
        float di = dinv[d];
        unsigned int sv = t2[d * 32 + sl];  // self row (broadcast across halves)
        float acc0 = 0.f, acc1 = 0.f;
        if (half == 0) {
            float dd = di * di;
            acc0 = __uint_as_float(sv << 16) * dd + bb.x;
            acc1 = __uint_as_float(sv & 0xffff0000u) * dd + bb.y;
        }
        int j0 = rowptr[d];
        int deg = rowptr[d + 1] - j0;
        int cnt = (deg + 1 - half) >> 1;  // half0: ceil(deg/2), half1: floor
        int j = j0 + half;
        for (; cnt >= 8; cnt -= 8, j += 16) {
            int2 a[8];
#pragma unroll
            for (int u = 0; u < 8; ++u) a[u] = csw[j + 2 * u];
            unsigned int v[8];
#pragma unroll
            for (int u = 0; u < 8; ++u) v[u] = t2[a[u].x * 32 + sl];
#pragma unroll
            for (int u = 0; u < 8; ++u) {
                float w = __int_as_float(a[u].y);
                acc0 += __uint_as_float(v[u] << 16) * w;
                acc1 += __uint_as_float(v[u] & 0xffff0000u) * w;
            }
        }
        for (; cnt > 0; --cnt, j += 2) {
            int2 a = csw[j];
            unsigned int v = t2[a.x * 32 + sl];
            float w = __int_as_float(a.y);
            acc0 += __uint_as_float(v << 16) * w;
            acc1 += __uint_as_float(v & 0xffff0000u) * w;
        }
        acc0 += __shfl_down(acc0, 32);
        acc1 += __shfl_down(acc1, 32);
        if (half == 0) {
            ((float2*)(h + (size_t)d * DD))[sl] = make_float2(acc0, acc1);
            sumA += acc0; sqA += acc0 * acc0;
            sumB += acc1; sqB += acc1 * acc1;
        }
    }
    __shared__ float s_sum[256], s_sq[256];  // [wave][feature]
    if (half == 0) {
        s_sum[wv * 64 + 2 * sl] = sumA;
        s_sum[wv * 64 + 2 * sl + 1] = sumB;
        s_sq[wv * 64 + 2 * sl] = sqA;
        s_sq[wv * 64 + 2 * sl + 1] = sqB;
    }
    __syncthreads();
    if (threadIdx.x < 64) {
        int f = threadIdx.x;
        float S = s_sum[f] + s_sum[64 + f] + s_sum[128 + f] + s_sum[192 + f];
        float Q = s_sq[f] + s_sq[64 + f] + s_sq[128 + f] + s_sq[192 + f];
        atomicAdd(&accum_l[f], S);
        atomicAdd(&accum_l[64 + f], Q);
    }
}

// ---------------- BN finalize: tiny, reads 128-float accumulator ----------------
__global__ __launch_bounds__(64) void bn_finalize_kernel(const float* __restrict__ accum_l,
                                                         const float* __restrict__ gamma,
                                                         const float* __restrict__ beta,
                                                         float* __restrict__ stats_next) {
    int f = threadIdx.x;
    float S = accum_l[f], Q = accum_l[64 + f];
    float mean = S / (float)NN;
    float var = fmaxf(Q / (float)NN - mean * mean, 0.f);
    float sc = gamma[f] * rsqrtf(var + BN_EPS);
    stats_next[f] = sc;
    stats_next[64 + f] = beta[f] - mean * sc;
}

// ---------------- pool: fused BN-apply(layer3) + ReLU + mean-pool + counts ----------------
#define POOL_CHUNK 512
__global__ __launch_bounds__(256) void pool_kernel(const float* __restrict__ hraw,
                                                   const float* __restrict__ stats_l,
                                                   const int* __restrict__ batch,
                                                   const int* __restrict__ flags,
                                                   float* __restrict__ pool,
                                                   float* __restrict__ counts) {
    int is32 = flags[1];
    int f = threadIdx.x & 63, rg = threadIdx.x >> 6;
    float sc = stats_l[f], sh = stats_l[64 + f];
    int base = blockIdx.x * POOL_CHUNK;
    float acc = 0.f, cnt = 0.f;
    int cur = -1;
    for (int i = rg; i < POOL_CHUNK; i += 4) {
        int n = base + i;
        if (n >= NN) break;
        int g = ld_batch(batch, n, is32);
        if (g != cur) {
            if (cur >= 0) {
                atomicAdd(&pool[cur * DD + f], acc);
                if (f == 0) atomicAdd(&counts[cur], cnt);
            }
            acc = 0.f;
            cnt = 0.f;
            cur = g;
        }
        acc += fmaxf(hraw[(size_t)n * DD + f] * sc + sh, 0.f);
        cnt += 1.f;
    }
    if (cur >= 0) {
        atomicAdd(&pool[cur * DD + f], acc);
        if (f == 0) atomicAdd(&counts[cur], cnt);
    }
}

__global__ __launch_bounds__(256) void final_kernel(const float* __restrict__ pool,
                                                    const float* __restrict__ counts,
                                                    float* __restrict__ out) {
    int i = blockIdx.x * 256 + threadIdx.x;
    if (i < NG * DD) {
        int g = i >> 6;
        out[i] = pool[i] / fmaxf(counts[g], 1.0f);
    }
}

extern "C" void kernel_launch(void* const* d_in, const int* in_sizes, int n_in,
                              void* d_out, int out_size, void* d_ws, size_t ws_size,
                              hipStream_t stream) {
    const float* x = (const float*)d_in[0];       // [NN, DD] f32
    const int* edge_index = (const int*)d_in[1];  // [2, NE] int (width detected)
    const int* batch = (const int*)d_in[2];       // [NN] int (width detected)
    const float* Ws = (const float*)d_in[3];      // [3,64,64]
    const float* bs = (const float*)d_in[4];      // [3,64]
    const float* gammas = (const float*)d_in[5];  // [3,64]
    const float* betas = (const float*)d_in[6];   // [3,64]
    float* out = (float*)d_out;                   // [NG, DD]

    // workspace layout (csw 8B-aligned; deg_cnt/rowptr/dinv 16B-aligned)
    float* h = (float*)d_ws;                   // 6,400,000 f (raw agg per layer)
    bf16* t = (bf16*)(h + (size_t)NN * DD);    // 6,400,000 bf16 (12.8 MB)
    int2* csw = (int2*)(t + (size_t)NN * DD);  // NE int2 (12.8 MB)
    float* dinv = (float*)(csw + NE);          // 100,000 f
    int* deg_cnt = (int*)(dinv + NN);          // 100,000 i (also fill cursor)
    int* rowptr = deg_cnt + NN;                // 100,001 i
    float* accum = (float*)(rowptr + NN + 1);  // NL*128 f (BN sum/sumsq per layer)
    float* stats = accum + NL * 128;           // (NL+1)*128 f: slot l = input xform of layer l
    float* pool = stats + (NL + 1) * 128;      // 8192 f
    float* counts = pool + NG * DD;            // 128 f
    int* flags = (int*)(counts + NG);          // 2 i
    int* blocksum = flags + 2;                 // 128 i

    hipMemsetAsync(deg_cnt, 0, NN * sizeof(int), stream);
    hipMemsetAsync(pool, 0, (NG * DD + NG) * sizeof(float), stream);

    detect_kernel<<<1, 256, 0, stream>>>(edge_index, batch, flags, stats);
    deg_kernel<<<(NE + 255) / 256, 256, 0, stream>>>(edge_index, flags, deg_cnt);
    scan_part_kernel<<<SCAN_BLK, 256, 0, stream>>>(deg_cnt, blocksum, dinv);
    scan_mid_kernel<<<1, 128, 0, stream>>>(blocksum, rowptr);
    scan_write_kernel<<<SCAN_BLK, 256, 0, stream>>>(deg_cnt, blocksum, rowptr);
    fill_kernel<<<(NE + 255) / 256, 256, 0, stream>>>(edge_index, flags, dinv, rowptr,
                                                      deg_cnt, csw);

    for (int l = 0; l < NL; ++l) {
        const float* hin = (l == 0) ? x : h;
        float alpha = (l == 0) ? 1.0f : 0.0f;  // identity vs ReLU on input transform
        gemm_kernel<<<NT, 256, 0, stream>>>(hin, Ws + (size_t)l * DD * DD,
                                            stats + l * 128, alpha, t, accum + l * 128);
        gather_kernel<<<NBLK_GATHER, 256, 0, stream>>>(t, dinv, bs + l * DD, rowptr, csw, h,
                                                       accum + l * 128);
        bn_finalize_kernel<<<1, 64, 0, stream>>>(accum + l * 128, gammas + l * DD,
                                                 betas + l * DD, stats + (l + 1) * 128);
    }

    pool_kernel<<<(NN + POOL_CHUNK - 1) / POOL_CHUNK, 256, 0, stream>>>(
        h, stats + NL * 128, batch, flags, pool, counts);
    final_kernel<<<(NG * DD + 255) / 256, 256, 0, stream>>>(pool, counts, out);
}

// Round 11
// 717.783 us; speedup vs baseline: 1.0637x; 1.0637x over previous
//
#include <hip/hip_runtime.h>
#include <hip/hip_bf16.h>

typedef __hip_bfloat16 bf16;

#define NN 100000
#define NE 1600000
#define DD 64
#define NL 3
#define NG 128
#define BN_EPS 1e-5f
#define SCAN_BLK 98  // ceil(NN / 1024)
#define TILE_ROWS 64
#define NT ((NN + TILE_ROWS - 1) / TILE_ROWS)  // 1563
#define GB_NODES 49
#define GB_BLOCKS ((NN + GB_NODES - 1) / GB_NODES)  // 2041
#define ECAP 1536  // staged edges per block (mean 784, sd ~28 -> 27 sigma)

// ---------------- dtype detect (int64 vs int32) ----------------
__global__ __launch_bounds__(256) void detect_kernel(const int* __restrict__ ei,
                                                     const int* __restrict__ batch,
                                                     int* __restrict__ flags) {
    __shared__ int s_e, s_b;
    if (threadIdx.x == 0) { s_e = 0; s_b = 0; }
    __syncthreads();
    for (int i = threadIdx.x; i < 512; i += 256) {
        if (ei[2 * i + 1] != 0) atomicOr(&s_e, 1);
        if (batch[NN - 1024 + 2 * i + 1] != 0) atomicOr(&s_b, 1);
    }
    __syncthreads();
    if (threadIdx.x == 0) { flags[0] = s_e; flags[1] = s_b; }  // 1 = int32, 0 = int64
}

__device__ __forceinline__ int ld_src(const int* ei, int e, int is32) {
    return is32 ? ei[e] : ei[2 * e];
}
__device__ __forceinline__ int ld_dst(const int* ei, int e, int is32) {
    return is32 ? ei[NE + e] : ei[2 * NE + 2 * e];
}
__device__ __forceinline__ int ld_batch(const int* b, int n, int is32) {
    return is32 ? b[n] : b[2 * n];
}
__device__ __forceinline__ float bf2f(unsigned short u) {
    return __uint_as_float(((unsigned int)u) << 16);
}

// ---------------- degree (int) ----------------
__global__ __launch_bounds__(256) void deg_kernel(const int* __restrict__ ei,
                                                  const int* __restrict__ flags,
                                                  int* __restrict__ deg_cnt) {
    int is32 = flags[0];
    int e = blockIdx.x * 256 + threadIdx.x;
    if (e < NE) atomicAdd(&deg_cnt[ld_dst(ei, e, is32)], 1);
}

// ---------------- parallel exclusive scan of degrees -> rowptr (+ fused dinv) ----------------
__global__ __launch_bounds__(256) void scan_part_kernel(const int* __restrict__ deg_cnt,
                                                        int* __restrict__ blocksum,
                                                        float* __restrict__ dinv) {
    __shared__ int s[256];
    int base = blockIdx.x * 1024 + threadIdx.x * 4;
    int t = 0;
    if (base < NN) {  // NN % 4 == 0 -> whole int4 in-bounds
        int4 v = *(const int4*)(deg_cnt + base);
        t = v.x + v.y + v.z + v.w;
        float4 dv = make_float4(rsqrtf((float)v.x + 1.f), rsqrtf((float)v.y + 1.f),
                                rsqrtf((float)v.z + 1.f), rsqrtf((float)v.w + 1.f));
        *(float4*)(dinv + base) = dv;  // +1 self-loop
    }
    s[threadIdx.x] = t;
    __syncthreads();
    for (int off = 128; off > 0; off >>= 1) {
        if (threadIdx.x < off) s[threadIdx.x] += s[threadIdx.x + off];
        __syncthreads();
    }
    if (threadIdx.x == 0) blocksum[blockIdx.x] = s[0];
}

__global__ __launch_bounds__(128) void scan_mid_kernel(int* __restrict__ blocksum,
                                                       int* __restrict__ rowptr) {
    __shared__ int s[128];
    int tid = threadIdx.x;
    int v = (tid < SCAN_BLK) ? blocksum[tid] : 0;
    s[tid] = v;
    for (int off = 1; off < 128; off <<= 1) {
        __syncthreads();
        int a = (tid >= off) ? s[tid - off] : 0;
        __syncthreads();
        s[tid] += a;
    }
    __syncthreads();
    if (tid < SCAN_BLK) blocksum[tid] = s[tid] - v;  // exclusive
    if (tid == 127) rowptr[NN] = s[127];             // total == NE
}

__global__ __launch_bounds__(256) void scan_write_kernel(int* __restrict__ deg_cnt,
                                                         const int* __restrict__ blocksum,
                                                         int* __restrict__ rowptr) {
    __shared__ int s[256];
    int base = blockIdx.x * 1024 + threadIdx.x * 4;
    int4 v = make_int4(0, 0, 0, 0);
    if (base < NN) v = *(const int4*)(deg_cnt + base);
    int t = v.x + v.y + v.z + v.w;
    s[threadIdx.x] = t;
    for (int off = 1; off < 256; off <<= 1) {
        __syncthreads();
        int a = (threadIdx.x >= off) ? s[threadIdx.x - off] : 0;
        __syncthreads();
        s[threadIdx.x] += a;
    }
    __syncthreads();
    int pre = blocksum[blockIdx.x] + s[threadIdx.x] - t;  // exclusive prefix
    if (base < NN) {
        rowptr[base] = pre;
        rowptr[base + 1] = pre + v.x;
        rowptr[base + 2] = pre + v.x + v.y;
        rowptr[base + 3] = pre + v.x + v.y + v.z;
        *(int4*)(deg_cnt + base) = make_int4(0, 0, 0, 0);
    }
}

// ---------------- CSR fill: interleaved (src, weight) ----------------
__global__ __launch_bounds__(256) void fill_kernel(const int* __restrict__ ei,
                                                   const int* __restrict__ flags,
                                                   const float* __restrict__ dinv,
                                                   const int* __restrict__ rowptr,
                                                   int* __restrict__ cursor,
                                                   int2* __restrict__ csw) {
    int is32 = flags[0];
    int e = blockIdx.x * 256 + threadIdx.x;
    if (e >= NE) return;
    int s = ld_src(ei, e, is32), d = ld_dst(ei, e, is32);
    int pos = rowptr[d] + atomicAdd(&cursor[d], 1);
    float w = dinv[s] * dinv[d];
    csw[pos] = make_int2(s, __float_as_int(w));
}

// ---------------- LDS-tiled gemm: t_bf16 = act(BN(h)) @ W; BN stats inline ----------------
__global__ __launch_bounds__(256) void gemm_kernel(const float* __restrict__ h,
                                                   const float* __restrict__ W,
                                                   const float* __restrict__ accum_prev,
                                                   const float* __restrict__ gamma,
                                                   const float* __restrict__ beta,
                                                   int use_bn, float alpha,
                                                   bf16* __restrict__ t,
                                                   float* __restrict__ accum_l) {
    if (blockIdx.x == 0 && threadIdx.x < 128) accum_l[threadIdx.x] = 0.f;

    __shared__ float ls[TILE_ROWS * DD];  // 16 KB staged tile (post-activation)
    __shared__ float ssc[DD], ssh[DD];
    if (threadIdx.x < 64) {
        if (use_bn) {
            float S = accum_prev[threadIdx.x], Q = accum_prev[64 + threadIdx.x];
            float mean = S / (float)NN;
            float var = fmaxf(Q / (float)NN - mean * mean, 0.f);
            float sc = gamma[threadIdx.x] * rsqrtf(var + BN_EPS);
            ssc[threadIdx.x] = sc;
            ssh[threadIdx.x] = beta[threadIdx.x] - mean * sc;
        } else {
            ssc[threadIdx.x] = 1.f;
            ssh[threadIdx.x] = 0.f;
        }
    }

    int c = threadIdx.x & 63;
    int wv = threadIdx.x >> 6;  // wave id 0..3
    float w[DD];
#pragma unroll
    for (int k = 0; k < DD; ++k) w[k] = W[k * DD + c];
    __syncthreads();  // ssc/ssh ready

    for (int tile = blockIdx.x; tile < NT; tile += gridDim.x) {
        int row0 = tile * TILE_ROWS;
#pragma unroll
        for (int it = 0; it < 4; ++it) {
            int flat = (threadIdx.x + it * 256) * 4;  // 0..16380
            int gflat = row0 * DD + flat;
            if (gflat < NN * DD) {
                float4 hv = *(const float4*)(h + gflat);
                int c0 = flat & 63;
                float4 s4 = *(const float4*)(ssc + c0);
                float4 b4 = *(const float4*)(ssh + c0);
                float x0 = hv.x * s4.x + b4.x;
                float x1 = hv.y * s4.y + b4.y;
                float x2 = hv.z * s4.z + b4.z;
                float x3 = hv.w * s4.w + b4.w;
                x0 = fmaxf(x0, x0 * alpha);
                x1 = fmaxf(x1, x1 * alpha);
                x2 = fmaxf(x2, x2 * alpha);
                x3 = fmaxf(x3, x3 * alpha);
                *(float4*)(ls + flat) = make_float4(x0, x1, x2, x3);
            }
        }
        __syncthreads();
        int nrows = min(TILE_ROWS, NN - row0);
        int rend = min(wv * 16 + 16, nrows);
        for (int rl = wv * 16; rl < rend; ++rl) {
            const float4* hrow = (const float4*)(ls + rl * DD);
            float acc = 0.f;
#pragma unroll
            for (int kk = 0; kk < DD / 4; ++kk) {
                float4 hv = hrow[kk];  // wave-uniform LDS read -> broadcast
                acc += hv.x * w[4 * kk] + hv.y * w[4 * kk + 1] +
                       hv.z * w[4 * kk + 2] + hv.w * w[4 * kk + 3];
            }
            t[(size_t)(row0 + rl) * DD + c] = __float2bfloat16(acc);
        }
        __syncthreads();
    }
}

// ---------------- gather v3: dst-tiled, csw staged in LDS ----------------
// Block owns 49 contiguous dst nodes -> their CSR edge slice is contiguous and
// staged into LDS (kills the csw->t dependent-load window). Lane = feature.
__global__ __launch_bounds__(256) void gather_kernel(const bf16* __restrict__ t,
                                                     const float* __restrict__ dinv,
                                                     const float* __restrict__ bias,
                                                     const int* __restrict__ rowptr,
                                                     const int2* __restrict__ csw,
                                                     float* __restrict__ h,
                                                     float* __restrict__ accum_l) {
    __shared__ int2 se[ECAP];           // 12 KB staged (src, weight)
    __shared__ int srp[GB_NODES + 1];   // staged rowptr slice
    __shared__ float s_sum[256], s_sq[256];

    int f = threadIdx.x & 63;
    int wv = threadIdx.x >> 6;
    int nb0 = blockIdx.x * GB_NODES;
    int nloc = min(GB_NODES, NN - nb0);

    for (int i = threadIdx.x; i <= nloc; i += 256) srp[i] = rowptr[nb0 + i];
    __syncthreads();
    int ebase = srp[0];
    int nE = srp[nloc] - ebase;
    int ncap = min(nE, ECAP);
    for (int i = threadIdx.x; i < ncap; i += 256) se[i] = csw[ebase + i];
    __syncthreads();

    const unsigned short* tf = (const unsigned short*)t + f;  // lane-fixed feature ptr
    float bb = bias[f];
    float sum = 0.f, sq = 0.f;
    for (int dl = wv; dl < nloc; dl += 4) {
        int d = nb0 + dl;
        float di = dinv[d];
        float acc = bf2f(tf[(size_t)d * DD]) * di * di + bb;
        int j = srp[dl] - ebase, jend = srp[dl + 1] - ebase;
        if (jend <= ECAP) {  // fast path: edges fully staged in LDS
            for (; j + 8 <= jend; j += 8) {
                int2 a[8];
#pragma unroll
                for (int u = 0; u < 8; ++u) a[u] = se[j + u];
                float v[8];
#pragma unroll
                for (int u = 0; u < 8; ++u) v[u] = bf2f(tf[(size_t)a[u].x * DD]);
#pragma unroll
                for (int u = 0; u < 8; ++u) acc += v[u] * __int_as_float(a[u].y);
            }
            for (; j < jend; ++j) {
                int2 a = se[j];
                acc += bf2f(tf[(size_t)a.x * DD]) * __int_as_float(a.y);
            }
        } else {  // overflow node (vanishingly rare): read csw from global
            for (; j + 8 <= jend; j += 8) {
                int2 a[8];
#pragma unroll
                for (int u = 0; u < 8; ++u) a[u] = csw[ebase + j + u];
                float v[8];
#pragma unroll
                for (int u = 0; u < 8; ++u) v[u] = bf2f(tf[(size_t)a[u].x * DD]);
#pragma unroll
                for (int u = 0; u < 8; ++u) acc += v[u] * __int_as_float(a[u].y);
            }
            for (; j < jend; ++j) {
                int2 a = csw[ebase + j];
                acc += bf2f(tf[(size_t)a.x * DD]) * __int_as_float(a.y);
            }
        }
        h[(size_t)d * DD + f] = acc;
        sum += acc;
        sq += acc * acc;
    }
    s_sum[threadIdx.x] = sum;
    s_sq[threadIdx.x] = sq;
    __syncthreads();
    if (threadIdx.x < 64) {
        sum = s_sum[f] + s_sum[64 + f] + s_sum[128 + f] + s_sum[192 + f];
        sq = s_sq[f] + s_sq[64 + f] + s_sq[128 + f] + s_sq[192 + f];
        atomicAdd(&accum_l[f], sum);
        atomicAdd(&accum_l[64 + f], sq);
    }
}

// ---------------- pool: inline BN finalize(layer3) + ReLU + mean-pool + counts ----------------
#define POOL_CHUNK 512
__global__ __launch_bounds__(256) void pool_kernel(const float* __restrict__ hraw,
                                                   const float* __restrict__ accum_l,
                                                   const float* __restrict__ gamma,
                                                   const float* __restrict__ beta,
                                                   const int* __restrict__ batch,
                                                   const int* __restrict__ flags,
                                                   float* __restrict__ pool,
                                                   float* __restrict__ counts) {
    __shared__ float ssc[64], ssh[64];
    if (threadIdx.x < 64) {
        float S = accum_l[threadIdx.x], Q = accum_l[64 + threadIdx.x];
        float mean = S / (float)NN;
        float var = fmaxf(Q / (float)NN - mean * mean, 0.f);
        float sc = gamma[threadIdx.x] * rsqrtf(var + BN_EPS);
        ssc[threadIdx.x] = sc;
        ssh[threadIdx.x] = beta[threadIdx.x] - mean * sc;
    }
    __syncthreads();
    int is32 = flags[1];
    int f = threadIdx.x & 63, rg = threadIdx.x >> 6;
    float sc = ssc[f], sh = ssh[f];
    int base = blockIdx.x * POOL_CHUNK;
    float acc = 0.f, cnt = 0.f;
    int cur = -1;
    for (int i = rg; i < POOL_CHUNK; i += 4) {
        int n = base + i;
        if (n >= NN) break;
        int g = ld_batch(batch, n, is32);
        if (g != cur) {
            if (cur >= 0) {
                atomicAdd(&pool[cur * DD + f], acc);
                if (f == 0) atomicAdd(&counts[cur], cnt);
            }
            acc = 0.f;
            cnt = 0.f;
            cur = g;
        }
        acc += fmaxf(hraw[(size_t)n * DD + f] * sc + sh, 0.f);
        cnt += 1.f;
    }
    if (cur >= 0) {
        atomicAdd(&pool[cur * DD + f], acc);
        if (f == 0) atomicAdd(&counts[cur], cnt);
    }
}

__global__ __launch_bounds__(256) void final_kernel(const float* __restrict__ pool,
                                                    const float* __restrict__ counts,
                                                    float* __restrict__ out) {
    int i = blockIdx.x * 256 + threadIdx.x;
    if (i < NG * DD) {
        int g = i >> 6;
        out[i] = pool[i] / fmaxf(counts[g], 1.0f);
    }
}

extern "C" void kernel_launch(void* const* d_in, const int* in_sizes, int n_in,
                              void* d_out, int out_size, void* d_ws, size_t ws_size,
                              hipStream_t stream) {
    const float* x = (const float*)d_in[0];       // [NN, DD] f32
    const int* edge_index = (const int*)d_in[1];  // [2, NE] int (width detected)
    const int* batch = (const int*)d_in[2];       // [NN] int (width detected)
    const float* Ws = (const float*)d_in[3];      // [3,64,64]
    const float* bs = (const float*)d_in[4];      // [3,64]
    const float* gammas = (const float*)d_in[5];  // [3,64]
    const float* betas = (const float*)d_in[6];   // [3,64]
    float* out = (float*)d_out;                   // [NG, DD]

    // workspace layout (csw 8B-aligned; deg_cnt/rowptr/dinv 16B-aligned)
    float* h = (float*)d_ws;                   // 6,400,000 f (raw agg per layer)
    bf16* t = (bf16*)(h + (size_t)NN * DD);    // 6,400,000 bf16 (12.8 MB)
    int2* csw = (int2*)(t + (size_t)NN * DD);  // NE int2 (12.8 MB)
    float* dinv = (float*)(csw + NE);          // 100,000 f
    int* deg_cnt = (int*)(dinv + NN);          // 100,000 i (also fill cursor)
    int* rowptr = deg_cnt + NN;                // 100,001 i
    float* accum = (float*)(rowptr + NN + 1);  // NL*128 f (BN sum/sumsq per layer)
    float* pool = accum + NL * 128;            // 8192 f
    float* counts = pool + NG * DD;            // 128 f
    int* flags = (int*)(counts + NG);          // 2 i
    int* blocksum = flags + 2;                 // 128 i

    hipMemsetAsync(deg_cnt, 0, NN * sizeof(int), stream);
    hipMemsetAsync(pool, 0, (NG * DD + NG) * sizeof(float), stream);

    detect_kernel<<<1, 256, 0, stream>>>(edge_index, batch, flags);
    deg_kernel<<<(NE + 255) / 256, 256, 0, stream>>>(edge_index, flags, deg_cnt);
    scan_part_kernel<<<SCAN_BLK, 256, 0, stream>>>(deg_cnt, blocksum, dinv);
    scan_mid_kernel<<<1, 128, 0, stream>>>(blocksum, rowptr);
    scan_write_kernel<<<SCAN_BLK, 256, 0, stream>>>(deg_cnt, blocksum, rowptr);
    fill_kernel<<<(NE + 255) / 256, 256, 0, stream>>>(edge_index, flags, dinv, rowptr,
                                                      deg_cnt, csw);

    for (int l = 0; l < NL; ++l) {
        const float* hin = (l == 0) ? x : h;
        float alpha = (l == 0) ? 1.0f : 0.0f;  // identity vs ReLU on input transform
        gemm_kernel<<<NT, 256, 0, stream>>>(hin, Ws + (size_t)l * DD * DD,
                                            accum + (l - 1 >= 0 ? l - 1 : 0) * 128,
                                            gammas + (l - 1 >= 0 ? l - 1 : 0) * DD,
                                            betas + (l - 1 >= 0 ? l - 1 : 0) * DD,
                                            (l > 0) ? 1 : 0, alpha, t, accum + l * 128);
        gather_kernel<<<GB_BLOCKS, 256, 0, stream>>>(t, dinv, bs + l * DD, rowptr, csw, h,
                                                     accum + l * 128);
    }

    pool_kernel<<<(NN + POOL_CHUNK - 1) / POOL_CHUNK, 256, 0, stream>>>(
        h, accum + 2 * 128, gammas + 2 * DD, betas + 2 * DD, batch, flags, pool, counts);
    final_kernel<<<(NG * DD + 255) / 256, 256, 0, stream>>>(pool, counts, out);
}